// Round 7
// baseline (967.072 us; speedup 1.0000x reference)
//
#include <hip/hip_runtime.h>
#include <hip/hip_bf16.h>

// ---------------------------------------------------------------------------
// StackedLSTM (2-layer, 64 steps) + dropout + classifier on MI355X.
//
// r7 = r6 design with the pragma-syntax fix (pragma on its own line).
//
// 4-role persistent pipeline (no grid.sync, no L2 flush), 32x32x16 MFMA.
// Roles (role = blockIdx&3, i = blockIdx>>2 in [0,64), 16 units/block):
//   A: xpart(t) = x_t @ Wih0^T           (off-path, runs 2 steps ahead)
//   B: h0(t)  = epi(h0(t-1)@Whh0^T + xpart(t))         [L0 chain: 1 GEMM/step]
//   C: Ppart(t) = h0(t) @ Wih1^T          (off the h1 chain)
//   D: h1(t)  = epi(h1(t-1)@Whh1^T + Ppart(t))         [L1 chain: 1 GEMM/step]
// D issues its Q-GEMM (h1(t-1), available early) BEFORE waiting for Ppart.
//
// Sync flags (ints in ws, prep-zeroed; drain-vmcnt0-then-flag ordering, r5-proven):
//   h0done[t] (+64 by B), h1done[t] (+64 by D), pcnt[t] (+64 by C),
//   xdone[t][i] (=1 by A_i), pdone[t][i] (=1 by C_i).
// Waits: A(t): h0done[t-2]  (xpart ring2)
//        B(t): h0done[t-1], pcnt[t-3] (h0 ring4 safety), xdone[t][i] (late)
//        C(t): h0done[t], h1done[t-2] (Ppart ring2 safety)
//        D(t): h1done[t-1], then pdone[t][i] after its Q-GEMM
// Rings: h0/h1 4 slots (slot(t)=(t+1)&3, slot0 = zeros), xpart/Ppart 2 slots.
//
// Frag32 layout for [128][K] bf16 (A-operand of 32x32x16):
//   chunk = (row>>5)*(K/16) + (k>>4); within chunk lane l, elem e:
//   row = m*32+(l&31), k = ks*16+(l>>5)*8+e; addr = chunk*512 + l*8 + e.
// W in LDS frag-linear: [(nt*KS+ks)*64+l]*8, col cc=l&31 -> gate=(cc>>3),
//   j = gate*1024 + n0 + nt*8 + (cc&7).
// C/D MFMA layout (m74/m101): col = l&31, row = (r&3)+8*(r>>2)+4*(l>>5).
// ---------------------------------------------------------------------------

typedef __attribute__((ext_vector_type(8)))  short s8v;   // 8 x bf16
typedef __attribute__((ext_vector_type(4)))  float f4v;
typedef __attribute__((ext_vector_type(16))) float f16v;  // 32x32 acc
typedef unsigned short bfu;

#define BATCH 128
#define HID   1024
#define NSTEP 64
#define TDIM  128
#define DDIM  512
#define TSTART 55
#define HSLOT 131072                 // elements per h ring slot (128x1024)

// flag indices (16-stride pads hot counters to separate lines)
#define F_H0D(t)  ((t) * 16)
#define F_H1D(t)  (1024 + (t) * 16)
#define F_PCN(t)  (2048 + (t) * 16)
#define F_XD(t,i) (3072 + (t) * 64 + (i))
#define F_PD(t,i) (7168 + (t) * 64 + (i))
#define NFLAGS    11264

__device__ __forceinline__ bfu f2bf(float f) {
    union { float f; unsigned int u; } v; v.f = f;
    unsigned int r = (v.u + 0x7FFFu + ((v.u >> 16) & 1u)) >> 16;  // RNE
    return (bfu)r;
}
__device__ __forceinline__ float sigm(float x) {
    return 1.f / (1.f + __expf(-x));
}
__device__ __forceinline__ f16v zero16() {
    f16v a;
    #pragma unroll
    for (int r = 0; r < 16; ++r) a[r] = 0.f;
    return a;
}

// 8 coherent 16B loads (8 consecutive 1KB chunks) + drain. r5-proven idiom:
// vmcnt(0) inside the same asm block as the defs keeps MFMA consumers ordered.
__device__ __forceinline__ void load8_sc(const bfu* p, s8v (&o)[8]) {
    const bfu* p2 = p + 2048;   // +4096 B
    asm volatile(
        "global_load_dwordx4 %0, %[a0], off sc0 sc1\n\t"
        "global_load_dwordx4 %1, %[a0], off offset:1024 sc0 sc1\n\t"
        "global_load_dwordx4 %2, %[a0], off offset:2048 sc0 sc1\n\t"
        "global_load_dwordx4 %3, %[a0], off offset:3072 sc0 sc1\n\t"
        "global_load_dwordx4 %4, %[a1], off sc0 sc1\n\t"
        "global_load_dwordx4 %5, %[a1], off offset:1024 sc0 sc1\n\t"
        "global_load_dwordx4 %6, %[a1], off offset:2048 sc0 sc1\n\t"
        "global_load_dwordx4 %7, %[a1], off offset:3072 sc0 sc1\n\t"
        "s_waitcnt vmcnt(0)"
        : "=&v"(o[0]), "=&v"(o[1]), "=&v"(o[2]), "=&v"(o[3]),
          "=&v"(o[4]), "=&v"(o[5]), "=&v"(o[6]), "=&v"(o[7])
        : [a0]"v"(p), [a1]"v"(p2)
        : "memory");
}

// store 16 f32 (64B) coherently
__device__ __forceinline__ void store16_sc(float* p, const f16v& a) {
    f4v v0 = {a[0], a[1], a[2], a[3]},   v1 = {a[4], a[5], a[6], a[7]};
    f4v v2 = {a[8], a[9], a[10], a[11]}, v3 = {a[12], a[13], a[14], a[15]};
    asm volatile(
        "global_store_dwordx4 %0, %1, off sc0 sc1\n\t"
        "global_store_dwordx4 %0, %2, off offset:16 sc0 sc1\n\t"
        "global_store_dwordx4 %0, %3, off offset:32 sc0 sc1\n\t"
        "global_store_dwordx4 %0, %4, off offset:48 sc0 sc1"
        :: "v"(p), "v"(v0), "v"(v1), "v"(v2), "v"(v3)
        : "memory");
}

// load 16 f32 coherently and add into acc
__device__ __forceinline__ void addpart_sc(const float* p, f16v& acc) {
    f4v v0, v1, v2, v3;
    asm volatile(
        "global_load_dwordx4 %0, %[ad], off sc0 sc1\n\t"
        "global_load_dwordx4 %1, %[ad], off offset:16 sc0 sc1\n\t"
        "global_load_dwordx4 %2, %[ad], off offset:32 sc0 sc1\n\t"
        "global_load_dwordx4 %3, %[ad], off offset:48 sc0 sc1\n\t"
        "s_waitcnt vmcnt(0)"
        : "=&v"(v0), "=&v"(v1), "=&v"(v2), "=&v"(v3)
        : [ad]"v"(p) : "memory");
    #pragma unroll
    for (int r = 0; r < 4; ++r) {
        acc[r] += v0[r]; acc[4 + r] += v1[r];
        acc[8 + r] += v2[r]; acc[12 + r] += v3[r];
    }
}

// ---------------------------------------------------------------------------
// prep: fp32->bf16 (x into frag32 layout), combined biases, zero ring slot 0
// of h0/h1 and all sync flags.
// ---------------------------------------------------------------------------
__global__ void prep_kernel(
    const float* __restrict__ xs,
    const float* __restrict__ Wih0, const float* __restrict__ Whh0,
    const float* __restrict__ Wih1, const float* __restrict__ Whh1,
    const float* __restrict__ Wcls,
    const float* __restrict__ bih0, const float* __restrict__ bhh0,
    const float* __restrict__ bih1, const float* __restrict__ bhh1,
    bfu* __restrict__ xbf, bfu* __restrict__ wih0b, bfu* __restrict__ whh0b,
    bfu* __restrict__ wih1b, bfu* __restrict__ whh1b, bfu* __restrict__ wclsb,
    float* __restrict__ bias0, float* __restrict__ bias1,
    bfu* __restrict__ h0ring, bfu* __restrict__ h1ring, int* __restrict__ flags)
{
    const size_t NX  = (size_t)NSTEP * BATCH * DDIM;         // 4,194,304
    const size_t E1  = NX  + (size_t)4096 * 512;             // +wih0
    const size_t E2  = E1  + (size_t)4096 * 1024;            // +whh0
    const size_t E3  = E2  + (size_t)4096 * 1024;            // +wih1
    const size_t E4  = E3  + (size_t)4096 * 1024;            // +whh1
    const size_t E5  = E4  + (size_t)1000 * 1024;            // +wcls
    const size_t E6  = E5  + 4096;                           // bias0
    const size_t E7  = E6  + 4096;                           // bias1
    const size_t E8  = E7  + HSLOT;                          // h0 slot 0
    const size_t E9  = E8  + HSLOT;                          // h1 slot 0
    const size_t E10 = E9  + NFLAGS;                         // flags

    size_t stride = (size_t)gridDim.x * blockDim.x;
    for (size_t i = (size_t)blockIdx.x * blockDim.x + threadIdx.x; i < E10; i += stride) {
        if (i < NX) {
            // frag32-permuted destination within each 65536-element step
            size_t t   = i >> 16;
            int    rem = (int)(i & 65535);
            int chunk = rem >> 9;              // [0,128): m*32 + ks
            int l = (rem >> 3) & 63, e = rem & 7;
            int m  = chunk >> 5;
            int ks = chunk & 31;
            int row = m * 32 + (l & 31);
            int k   = ks * 16 + (l >> 5) * 8 + e;
            xbf[i] = f2bf(xs[(size_t)row * (TDIM * DDIM) + (TSTART + t) * DDIM + k]);
        } else if (i < E1) { size_t j = i - NX;  wih0b[j] = f2bf(Wih0[j]); }
        else if (i < E2)   { size_t j = i - E1;  whh0b[j] = f2bf(Whh0[j]); }
        else if (i < E3)   { size_t j = i - E2;  wih1b[j] = f2bf(Wih1[j]); }
        else if (i < E4)   { size_t j = i - E3;  whh1b[j] = f2bf(Whh1[j]); }
        else if (i < E5)   { size_t j = i - E4;  wclsb[j] = f2bf(Wcls[j]); }
        else if (i < E6)   { size_t j = i - E5;  bias0[j] = bih0[j] + bhh0[j]; }
        else if (i < E7)   { size_t j = i - E6;  bias1[j] = bih1[j] + bhh1[j]; }
        else if (i < E8)   { h0ring[i - E7] = 0; }
        else if (i < E9)   { h1ring[i - E8] = 0; }
        else               { flags[i - E9] = 0; }
    }
}

// ---------------------------------------------------------------------------
// One K-GEMM with 32x32x16 MFMA. A: frag32 global (SC => coherent loads).
// bbase points at this wave's nt region of W-LDS. KS = K/16.
// ---------------------------------------------------------------------------
template<bool SC, int KS>
__device__ __forceinline__ void gemm32(const bfu* __restrict__ Abase,
                                       const bfu* __restrict__ bbase,
                                       f16v& acc, int m, int l)
{
    const bfu* ap = Abase + (size_t)(m * KS) * 512 + l * 8;
    const bfu* bp = bbase + l * 8;
    #pragma unroll
    for (int g = 0; g < KS / 8; ++g) {
        s8v o[8];
        if constexpr (SC) {
            load8_sc(ap, o);
        } else {
            #pragma unroll
            for (int c = 0; c < 8; ++c) o[c] = *(const s8v*)(ap + c * 512);
        }
        ap += 8 * 512;
        #pragma unroll
        for (int c = 0; c < 8; ++c) {
            s8v b = *(const s8v*)bp; bp += 512;
            acc = __builtin_amdgcn_mfma_f32_32x32x16_bf16(o[c], b, acc, 0, 0, 0);
        }
    }
}

// ---------------------------------------------------------------------------
// LSTM epilogue for a 16-unit block (B and D roles). Two rounds of 64 rows
// through eps[64][66] f32. Thread owns (row64 = tid>>3, units 2*(tid&7)+{0,1})
// per round; cell state cst[4] = [round][unit01] in registers.
// ---------------------------------------------------------------------------
__device__ __forceinline__ void lstm_epi32(
    f16v& acc, float (*eps)[66], int tid, int n0,
    const float* bgq, float* cst, bfu* __restrict__ h_out,
    float* __restrict__ h1f_opt)
{
    const int l = tid & 63, w = tid >> 6;
    const int m = w >> 1, nt = w & 1, hi = l >> 5, cc = l & 31;
    const int row64 = tid >> 3, up = tid & 7;
    const int u0 = 2 * up;
    const int cb = ((u0 >> 3) * 32) + (u0 & 7);
    const int k = n0 + u0;

    #pragma unroll
    for (int h = 0; h < 2; ++h) {
        if ((m >> 1) == h) {
            #pragma unroll
            for (int r = 0; r < 16; ++r)
                eps[(m & 1) * 32 + (r & 3) + 8 * (r >> 2) + 4 * hi][nt * 32 + cc] = acc[r];
        }
        __syncthreads();
        {
            const int row = h * 64 + row64;
            float gi0 = eps[row64][cb]      + bgq[0];
            float gi1 = eps[row64][cb + 1]  + bgq[1];
            float gf0 = eps[row64][cb + 8]  + bgq[2];
            float gf1 = eps[row64][cb + 9]  + bgq[3];
            float gg0 = eps[row64][cb + 16] + bgq[4];
            float gg1 = eps[row64][cb + 17] + bgq[5];
            float go0 = eps[row64][cb + 24] + bgq[6];
            float go1 = eps[row64][cb + 25] + bgq[7];
            float cn0 = sigm(gf0) * cst[h * 2]     + sigm(gi0) * tanhf(gg0);
            float cn1 = sigm(gf1) * cst[h * 2 + 1] + sigm(gi1) * tanhf(gg1);
            cst[h * 2] = cn0; cst[h * 2 + 1] = cn1;
            float hn0 = sigm(go0) * tanhf(cn0);
            float hn1 = sigm(go1) * tanhf(cn1);
            // frag32 h write (k even: k,k+1 adjacent elems, 4B-aligned pack)
            const int chunk = (row >> 5) * 64 + (k >> 4);
            const int lp = ((k >> 3) & 1) * 32 + (row & 31);
            const int elem = chunk * 512 + lp * 8 + (k & 7);
            unsigned int pk = (unsigned int)f2bf(hn0) | ((unsigned int)f2bf(hn1) << 16);
            __hip_atomic_store((unsigned int*)(h_out + elem), pk,
                               __ATOMIC_RELAXED, __HIP_MEMORY_SCOPE_AGENT);
            if (h1f_opt) {
                h1f_opt[(size_t)row * HID + k]     = hn0;
                h1f_opt[(size_t)row * HID + k + 1] = hn1;
            }
        }
        __syncthreads();
    }
}

__device__ __forceinline__ void waitflag(int* p, int target, int tid) {
    if (tid == 0)
        while (__hip_atomic_load(p, __ATOMIC_RELAXED, __HIP_MEMORY_SCOPE_AGENT) < target)
            __builtin_amdgcn_s_sleep(1);
    __syncthreads();
}

// ---------------------------------------------------------------------------
// Persistent 4-role kernel. 256 blocks x 512 thr; LDS: W 64/128KB + eps 16.9KB.
// ---------------------------------------------------------------------------
__global__ __launch_bounds__(512)
void persist_kernel(
    const bfu* __restrict__ xbf,
    const bfu* __restrict__ wih0, const bfu* __restrict__ whh0,
    const bfu* __restrict__ wih1, const bfu* __restrict__ whh1,
    const float* __restrict__ bias0, const float* __restrict__ bias1,
    bfu* __restrict__ h0ring, bfu* __restrict__ h1ring,
    float* __restrict__ xpart, float* __restrict__ ppart,
    float* __restrict__ h1f, int* __restrict__ F)
{
    __shared__ bfu   wlds[65536];        // up to 128 KB
    __shared__ float eps[64][66];        // 16.9 KB

    const int tid  = threadIdx.x;
    const int role = blockIdx.x & 3;
    const int i    = blockIdx.x >> 2;
    const int n0   = i * 16;
    const int l = tid & 63, w = tid >> 6;
    const int m = w >> 1, nt = w & 1;

    const bfu* Wsrc; const float* bias = nullptr; int K;
    if      (role == 0) { Wsrc = wih0; K = 512; }
    else if (role == 1) { Wsrc = whh0; K = 1024; bias = bias0; }
    else if (role == 2) { Wsrc = wih1; K = 1024; }
    else                { Wsrc = whh1; K = 1024; bias = bias1; }
    const int KSr = K >> 4;
    const int ksh = (K == 512) ? 5 : 6;

    // ---- stage W into LDS, frag-linear (once) ----
    for (int u = tid; u < 2 * KSr * 64; u += 512) {
        int c = u >> 6, ll = u & 63;
        int ntc = c >> ksh, ks = c & (KSr - 1);
        int j  = ((ll >> 3) & 3) * 1024 + n0 + ntc * 8 + (ll & 7);
        int k0 = ks * 16 + (ll >> 5) * 8;
        *(s8v*)(wlds + (size_t)c * 512 + ll * 8) = *(const s8v*)(Wsrc + (size_t)j * K + k0);
    }
    __syncthreads();

    // ---- per-thread persistent epilogue state (B/D) ----
    float bgq[8] = {0.f, 0.f, 0.f, 0.f, 0.f, 0.f, 0.f, 0.f};
    float cst[4] = {0.f, 0.f, 0.f, 0.f};
    if (bias) {
        const int u0 = 2 * (tid & 7);
        #pragma unroll
        for (int g = 0; g < 4; ++g) {
            bgq[g * 2]     = bias[g * HID + n0 + u0];
            bgq[g * 2 + 1] = bias[g * HID + n0 + u0 + 1];
        }
    }

    const bfu* bnt512 = wlds + (size_t)nt * 32 * 512;   // A-role nt region
    const bfu* bnt    = wlds + (size_t)nt * 64 * 512;   // K=1024 nt region

    if (role == 0) {                        // ---- A: xpart ----
        for (int t = 0; t < NSTEP; ++t) {
            if (t >= 2) waitflag(&F[F_H0D(t - 2)], 64, tid);
            f16v acc = zero16();
            gemm32<false, 32>(xbf + (size_t)t * 65536, bnt512, acc, m, l);
            store16_sc(xpart + ((size_t)((t & 1) * 64 + i)) * 8192 + (w * 64 + l) * 16, acc);
            asm volatile("s_waitcnt vmcnt(0)" ::: "memory");
            __syncthreads();
            if (tid == 0)
                __hip_atomic_store(&F[F_XD(t, i)], 1, __ATOMIC_RELAXED, __HIP_MEMORY_SCOPE_AGENT);
        }
    } else if (role == 1) {                 // ---- B: L0 chain ----
        for (int t = 0; t < NSTEP; ++t) {
            if (t >= 1) waitflag(&F[F_H0D(t - 1)], 64, tid);
            if (t >= 3) waitflag(&F[F_PCN(t - 3)], 64, tid);
            f16v acc = zero16();
            gemm32<true, 64>(h0ring + (size_t)(t & 3) * HSLOT, bnt, acc, m, l);
            waitflag(&F[F_XD(t, i)], 1, tid);
            addpart_sc(xpart + ((size_t)((t & 1) * 64 + i)) * 8192 + (w * 64 + l) * 16, acc);
            lstm_epi32(acc, eps, tid, n0, bgq, cst,
                       h0ring + (size_t)((t + 1) & 3) * HSLOT, nullptr);
            asm volatile("s_waitcnt vmcnt(0)" ::: "memory");
            __syncthreads();
            if (tid == 0)
                __hip_atomic_fetch_add(&F[F_H0D(t)], 1, __ATOMIC_RELAXED, __HIP_MEMORY_SCOPE_AGENT);
        }
    } else if (role == 2) {                 // ---- C: Ppart ----
        for (int t = 0; t < NSTEP; ++t) {
            waitflag(&F[F_H0D(t)], 64, tid);
            if (t >= 2) waitflag(&F[F_H1D(t - 2)], 64, tid);
            f16v acc = zero16();
            gemm32<true, 64>(h0ring + (size_t)((t + 1) & 3) * HSLOT, bnt, acc, m, l);
            store16_sc(ppart + ((size_t)((t & 1) * 64 + i)) * 8192 + (w * 64 + l) * 16, acc);
            asm volatile("s_waitcnt vmcnt(0)" ::: "memory");
            __syncthreads();
            if (tid == 0) {
                __hip_atomic_store(&F[F_PD(t, i)], 1, __ATOMIC_RELAXED, __HIP_MEMORY_SCOPE_AGENT);
                __hip_atomic_fetch_add(&F[F_PCN(t)], 1, __ATOMIC_RELAXED, __HIP_MEMORY_SCOPE_AGENT);
            }
        }
    } else {                                // ---- D: L1 chain ----
        for (int t = 0; t < NSTEP; ++t) {
            if (t >= 1) waitflag(&F[F_H1D(t - 1)], 64, tid);
            f16v acc = zero16();
            gemm32<true, 64>(h1ring + (size_t)(t & 3) * HSLOT, bnt, acc, m, l);
            waitflag(&F[F_PD(t, i)], 1, tid);
            addpart_sc(ppart + ((size_t)((t & 1) * 64 + i)) * 8192 + (w * 64 + l) * 16, acc);
            lstm_epi32(acc, eps, tid, n0, bgq, cst,
                       h1ring + (size_t)((t + 1) & 3) * HSLOT,
                       (t == NSTEP - 1) ? h1f : nullptr);
            asm volatile("s_waitcnt vmcnt(0)" ::: "memory");
            __syncthreads();
            if (tid == 0)
                __hip_atomic_fetch_add(&F[F_H1D(t)], 1, __ATOMIC_RELAXED, __HIP_MEMORY_SCOPE_AGENT);
        }
    }
}

// ---------------------------------------------------------------------------
// classifier with fused dropout: out = (mask(h1)/0.5) @ Wcls^T + b_cls
// (16x16x32 MFMA path, unchanged from r5 — proven)
// ---------------------------------------------------------------------------
__global__ __launch_bounds__(512)
void cls_kernel(const float* __restrict__ h1f, const float* __restrict__ du,
                const bfu* __restrict__ Wc, const float* __restrict__ bc,
                float* __restrict__ out)
{
    const int tid = threadIdx.x;
    const int l   = tid & 63;
    const int w   = tid >> 6;
    const int lr  = l & 15;
    const int kg  = l >> 4;
    const int j   = blockIdx.x * 16 + lr;
    const int jW  = (j < 1000) ? j : 999;

    f4v acc = {0.f, 0.f, 0.f, 0.f};
    const float* hp = h1f + (size_t)(w * 16 + lr) * HID + kg * 8;
    const float* dp = du  + (size_t)(w * 16 + lr) * HID + kg * 8;
    const bfu*   bp = Wc  + (size_t)jW * HID + kg * 8;
    #pragma unroll 4
    for (int kk = 0; kk < HID; kk += 32) {
        f4v h0v = *(const f4v*)hp;
        f4v h1v = *(const f4v*)(hp + 4);
        f4v d0v = *(const f4v*)dp;
        f4v d1v = *(const f4v*)(dp + 4);
        s8v a;
        #pragma unroll
        for (int e = 0; e < 4; ++e) {
            a[e]     = (short)f2bf(d0v[e] > 0.5f ? h0v[e] * 2.f : 0.f);
            a[4 + e] = (short)f2bf(d1v[e] > 0.5f ? h1v[e] * 2.f : 0.f);
        }
        s8v b = *(const s8v*)bp;
        acc = __builtin_amdgcn_mfma_f32_16x16x32_bf16(a, b, acc, 0, 0, 0);
        hp += 32; dp += 32; bp += 32;
    }
    if (j < 1000) {
        const float bj = bc[j];
        const int rbase = w * 16 + kg * 4;
        #pragma unroll
        for (int r = 0; r < 4; ++r)
            out[(size_t)(rbase + r) * 1000 + j] = acc[r] + bj;
    }
}

// ---------------------------------------------------------------------------
extern "C" void kernel_launch(void* const* d_in, const int* in_sizes, int n_in,
                              void* d_out, int out_size, void* d_ws, size_t ws_size,
                              hipStream_t stream)
{
    const float* xs   = (const float*)d_in[0];
    const float* Wih0 = (const float*)d_in[1];
    const float* Whh0 = (const float*)d_in[2];
    const float* bih0 = (const float*)d_in[3];
    const float* bhh0 = (const float*)d_in[4];
    const float* Wih1 = (const float*)d_in[5];
    const float* Whh1 = (const float*)d_in[6];
    const float* bih1 = (const float*)d_in[7];
    const float* bhh1 = (const float*)d_in[8];
    const float* Wcls = (const float*)d_in[9];
    const float* bcls = (const float*)d_in[10];
    const float* du   = (const float*)d_in[11];
    float* out = (float*)d_out;

    // ws carve-out (256B-aligned), ~49 MB total
    char* p = (char*)d_ws;
    auto alloc = [&](size_t bytes) {
        char* r = p; p += (bytes + 255) & ~(size_t)255; return r;
    };
    bfu*   xbf    = (bfu*)  alloc((size_t)NSTEP * BATCH * DDIM * 2);
    bfu*   wih0b  = (bfu*)  alloc((size_t)4096 * 512 * 2);
    bfu*   whh0b  = (bfu*)  alloc((size_t)4096 * 1024 * 2);
    bfu*   wih1b  = (bfu*)  alloc((size_t)4096 * 1024 * 2);
    bfu*   whh1b  = (bfu*)  alloc((size_t)4096 * 1024 * 2);
    bfu*   wclsb  = (bfu*)  alloc((size_t)1000 * 1024 * 2);
    float* bias0  = (float*)alloc(4096 * 4);
    float* bias1  = (float*)alloc(4096 * 4);
    bfu*   h0ring = (bfu*)  alloc((size_t)4 * HSLOT * 2);
    bfu*   h1ring = (bfu*)  alloc((size_t)4 * HSLOT * 2);
    float* xpart  = (float*)alloc((size_t)2 * 64 * 8192 * 4);
    float* ppart  = (float*)alloc((size_t)2 * 64 * 8192 * 4);
    float* h1f    = (float*)alloc((size_t)BATCH * HID * 4);
    int*   flags  = (int*)  alloc((size_t)NFLAGS * 4);
    (void)ws_size; (void)in_sizes; (void)n_in; (void)out_size;

    prep_kernel<<<2048, 256, 0, stream>>>(
        xs, Wih0, Whh0, Wih1, Whh1, Wcls, bih0, bhh0, bih1, bhh1,
        xbf, wih0b, whh0b, wih1b, whh1b, wclsb, bias0, bias1,
        h0ring, h1ring, flags);

    persist_kernel<<<256, 512, 0, stream>>>(
        xbf, wih0b, whh0b, wih1b, whh1b, bias0, bias1,
        h0ring, h1ring, xpart, ppart, h1f, flags);

    cls_kernel<<<63, 512, 0, stream>>>(h1f, du, wclsb, bcls, out);
}